// Round 8
// baseline (301.630 us; speedup 1.0000x reference)
//
#include <hip/hip_runtime.h>

#define HS   1024
#define SEQ  512
#define NBAT 64
#define INSZ 8
#define NM   4
#define DD   12
#define CH   8      // steps per P-chunk (handoff granularity)

#define ALPHA 0.1f
#define OMA   0.9f
#define SCL   (500.0f/1024.0f)
#define AS    (ALPHA*SCL)

// exp(2h) as exp2(GS*h). A, B, Yg all carry GS.
#if __has_builtin(__builtin_amdgcn_exp2f)
  #define GS 2.8853900817779268f      /* 2*log2(e) */
  #define EXPG(v) __builtin_amdgcn_exp2f(v)
#else
  #define GS 2.0f
  #define EXPG(v) __expf(v)
#endif

#if __has_builtin(__builtin_amdgcn_sched_barrier)
  #define SCHED_FENCE() __builtin_amdgcn_sched_barrier(0)
#else
  #define SCHED_FENCE() asm volatile("" ::: "memory")
#endif

typedef float f2 __attribute__((ext_vector_type(2)));
typedef float f4 __attribute__((ext_vector_type(4)));
__device__ __forceinline__ f2 mk2(float a, float b){ f2 r; r.x=a; r.y=b; return r; }
__device__ __forceinline__ f2 splat2(float a){ return mk2(a,a); }
__device__ __forceinline__ f4 splat4(float a){ f4 r; r.x=a; r.y=a; r.z=a; r.w=a; return r; }
#if __has_builtin(__builtin_elementwise_fma)
__device__ __forceinline__ f2 fma2(f2 a, f2 b, f2 c){ return __builtin_elementwise_fma(a,b,c); }
__device__ __forceinline__ f4 fma4(f4 a, f4 b, f4 c){ return __builtin_elementwise_fma(a,b,c); }
#else
__device__ __forceinline__ f2 fma2(f2 a, f2 b, f2 c){
  f2 r; r.x=fmaf(a.x,b.x,c.x); r.y=fmaf(a.y,b.y,c.y); return r; }
__device__ __forceinline__ f4 fma4(f4 a, f4 b, f4 c){
  f4 r; r.x=fmaf(a.x,b.x,c.x); r.y=fmaf(a.y,b.y,c.y);
        r.z=fmaf(a.z,b.z,c.z); r.w=fmaf(a.w,b.w,c.w); return r; }
#endif

// DPP-based add: v += dpp_move(v). old=0 so masked/invalid lanes add 0.
#define DPP_ADD(v, ctrl, rmask, bmask) \
  v += __int_as_float(__builtin_amdgcn_update_dpp(0, __float_as_int(v), ctrl, rmask, bmask, true))

// Canonical gfx9 wave64 sum. Lane 63 holds the full 64-lane total afterwards.
__device__ __forceinline__ void wave64_sum2(float &a, float &b){
  DPP_ADD(a, 0x111, 0xf, 0xf); DPP_ADD(b, 0x111, 0xf, 0xf);  // row_shr:1
  DPP_ADD(a, 0x112, 0xf, 0xf); DPP_ADD(b, 0x112, 0xf, 0xf);  // row_shr:2
  DPP_ADD(a, 0x114, 0xf, 0xe); DPP_ADD(b, 0x114, 0xf, 0xe);  // row_shr:4
  DPP_ADD(a, 0x118, 0xf, 0xc); DPP_ADD(b, 0x118, 0xf, 0xc);  // row_shr:8
  DPP_ADD(a, 0x142, 0xa, 0xf); DPP_ADD(b, 0x142, 0xa, 0xf);  // row_bcast:15
  DPP_ADD(a, 0x143, 0xc, 0xf); DPP_ADD(b, 0x143, 0xc, 0xf);  // row_bcast:31
}
#define RD63(v) __int_as_float(__builtin_amdgcn_readlane(__float_as_int(v), 63))

// mixed[e] for unit i, e in [E0,E1)
template<int E0, int E1>
__device__ __forceinline__ void mix_unit(int i, const float* __restrict__ eps,
                                         const float* __restrict__ means,
                                         const float* __restrict__ tril,
                                         const float* w, float* outm){
  float ep[NM][DD];
  #pragma unroll
  for (int k=0;k<NM;k++){
    const float4* p = (const float4*)(eps + (size_t)(k*HS + i)*DD);
    float4 r0=p[0], r1=p[1], r2=p[2];
    ep[k][0]=r0.x; ep[k][1]=r0.y; ep[k][2]=r0.z; ep[k][3]=r0.w;
    ep[k][4]=r1.x; ep[k][5]=r1.y; ep[k][6]=r1.z; ep[k][7]=r1.w;
    ep[k][8]=r2.x; ep[k][9]=r2.y; ep[k][10]=r2.z; ep[k][11]=r2.w;
  }
  #pragma unroll
  for (int e=E0;e<E1;e++){
    float a = 0.f;
    #pragma unroll
    for (int k=0;k<NM;k++){
      float se = means[k*DD+e];
      #pragma unroll
      for (int d=0; d<e; d++) se = fmaf(ep[k][d], tril[(k*DD+e)*DD+d], se);
      float dg = fabsf(tril[(k*DD+e)*DD+e] - 1e-12f) + 1e-12f;
      se = fmaf(ep[k][e], dg, se);
      a = fmaf(w[k], se, a);
    }
    outm[e-E0] = a;
  }
}

// R6 architecture with both spill sources removed.
// Producer (wave 1): P[t][i] = I_i . Yg(t) into double-buffered LDS, with I
//   held in LDS and processed in 32-reg s-slices (Yg recomputed per slice --
//   redundant but off the serial chain). Also emits out cols 2..9.
// Consumer (wave 0): registers + DPP + 1-step-prefetched LDS reads ONLY.
// Sync: chunk-granular write-once flags (protocol verified in R6).
__global__ __launch_bounds__(128,1)
void rnn_scan(const float* __restrict__ x, const float* __restrict__ eps,
              const float* __restrict__ means, const float* __restrict__ tril,
              const float* __restrict__ mw, float* __restrict__ out)
{
  const int b    = blockIdx.x;
  const int tid  = threadIdx.x;
  const int wv   = tid >> 6;
  const int lane = tid & 63;

  __shared__ float xs[SEQ*INSZ];                 // 16 KB
  __shared__ f4    Pb[2][CH][4][64];             // 64 KB: double-buffered P
  __shared__ f4    Ivl[4][8][64];                // 32 KB: I cols, lane-contig
  __shared__ __align__(16) float outb[SEQ*10];   // 20 KB
  __shared__ int prod_ready, cons_done;          //  (total ~132 KB)

  // stage x[b] cooperatively, init flags
  { const f4* xp=(const f4*)(x + (size_t)b*SEQ*INSZ);
    f4* xd=(f4*)xs;
    for (int idx=tid; idx<SEQ*INSZ/4; idx+=128) xd[idx]=xp[idx]; }
  if (tid==0){ prod_ready=0; cons_done=0; }

  float w[NM];
  { float s=0.f;
    #pragma unroll
    for (int k=0;k<NM;k++){ w[k]=fmaxf(mw[k],1e-6f); s+=w[k]; }
    float inv=1.0f/s;
    #pragma unroll
    for (int k=0;k<NM;k++) w[k]*=inv; }

  __syncthreads();   // xs + flags visible; only pre-loop barrier

  volatile int* vpr = (volatile int*)&prod_ready;
  volatile int* vcd = (volatile int*)&cons_done;

  if (wv==1){
    // ======================= PRODUCER =======================
    // preprocess I into LDS, one s-group at a time (low liveness)
    #pragma unroll 1
    for (int s=0;s<4;s++){
      f4 Irow[8];
      #pragma unroll
      for (int j=0;j<4;j++){
        float mm[8];
        mix_unit<4,12>(16*lane + 4*s + j, eps, means, tril, w, mm);
        #pragma unroll
        for (int e=0;e<8;e++) Irow[e][j] = mm[e];
        SCHED_FENCE();
      }
      #pragma unroll
      for (int e=0;e<8;e++) Ivl[s][e][lane] = Irow[e];
    }

    const float AG = GS*ALPHA;
    float Yg[8];                       // Yg at start of current chunk
    #pragma unroll
    for (int e=0;e<8;e++) Yg[e]=0.f;

    const bool olane = (lane>=8 && lane<16);   // lanes 8..15 own out cols 2..9
    const int  oc    = lane-8;
    float ox = 0.f;

    #pragma unroll 1
    for (int c=0;c<SEQ/CH;c++){
      if (c>=2){ while (*vcd < c-1) __builtin_amdgcn_s_sleep(1); }
      const int t0 = c*CH;
      // 4 s-slices; Yl recomputed per slice (identical fold order each time)
      #pragma unroll 1
      for (int s=0;s<4;s++){
        f4 IvS[8];
        #pragma unroll
        for (int e=0;e<8;e++) IvS[e] = Ivl[s][e][lane];
        float Yl[8];
        #pragma unroll
        for (int e=0;e<8;e++) Yl[e]=Yg[e];
        #pragma unroll
        for (int tt=0;tt<CH;tt++){
          f4 acc =      IvS[0]*splat4(Yl[0]);
          acc = fma4(IvS[1], splat4(Yl[1]), acc);
          acc = fma4(IvS[2], splat4(Yl[2]), acc);
          acc = fma4(IvS[3], splat4(Yl[3]), acc);
          acc = fma4(IvS[4], splat4(Yl[4]), acc);
          acc = fma4(IvS[5], splat4(Yl[5]), acc);
          acc = fma4(IvS[6], splat4(Yl[6]), acc);
          acc = fma4(IvS[7], splat4(Yl[7]), acc);
          Pb[c&1][tt][s][lane] = acc;
          const int t = t0+tt;
          f4 xa = ((const f4*)xs)[t*2], xb = ((const f4*)xs)[t*2+1];
          Yl[0]=fmaf(OMA,Yl[0],AG*xa.x); Yl[1]=fmaf(OMA,Yl[1],AG*xa.y);
          Yl[2]=fmaf(OMA,Yl[2],AG*xa.z); Yl[3]=fmaf(OMA,Yl[3],AG*xa.w);
          Yl[4]=fmaf(OMA,Yl[4],AG*xb.x); Yl[5]=fmaf(OMA,Yl[5],AG*xb.y);
          Yl[6]=fmaf(OMA,Yl[6],AG*xb.z); Yl[7]=fmaf(OMA,Yl[7],AG*xb.w);
        }
        if (s==3){
          #pragma unroll
          for (int e=0;e<8;e++) Yg[e]=Yl[e];
        }
      }
      // output columns 2..9 for this chunk (pure x-EMA, off-chain)
      if (olane){
        #pragma unroll
        for (int tt=0;tt<CH;tt++){
          ox = fmaf(OMA, ox, ALPHA*xs[(t0+tt)*8+oc]);
          outb[(t0+tt)*10 + oc + 2] = ox;
        }
      }
      asm volatile("" ::: "memory");       // data writes before flag
      if (lane==0) *vpr = c+1;
    }
  } else {
    // ======================= CONSUMER =======================
    // pairs p: units 16*lane+2p, 16*lane+2p+1 (matches producer P layout)
    f2 m0v[8], m1v[8], n0v[8], n1v[8];
    float sn0=0.f, sn1=0.f;
    #pragma unroll
    for (int p=0;p<8;p++){
      float mA[4], mB[4];
      mix_unit<0,4>(16*lane+2*p,   eps, means, tril, w, mA);
      SCHED_FENCE();
      mix_unit<0,4>(16*lane+2*p+1, eps, means, tril, w, mB);
      SCHED_FENCE();
      m0v[p]=mk2(mA[0],mB[0]); m1v[p]=mk2(mA[1],mB[1]);
      sn0 += mA[2]+mB[2];      sn1 += mA[3]+mB[3];
      n0v[p]=mk2(-2.f*mA[2], -2.f*mB[2]);
      n1v[p]=mk2(-2.f*mA[3], -2.f*mB[3]);
    }
    wave64_sum2(sn0, sn1);
    const float N0 = RD63(sn0), N1 = RD63(sn1);

    const float CA = GS*AS;
    float A=0.f, Bst=0.f, o=0.f;

  #define STEP(T, TN, buf, c0,c1,c2,c3, d0,d1,d2,d3) { \
    d0=Pb[buf][TN][0][lane]; d1=Pb[buf][TN][1][lane]; \
    d2=Pb[buf][TN][2][lane]; d3=Pb[buf][TN][3][lane]; \
    f2 g[8]; \
    g[0]=mk2(c0.x,c0.y); g[1]=mk2(c0.z,c0.w); \
    g[2]=mk2(c1.x,c1.y); g[3]=mk2(c1.z,c1.w); \
    g[4]=mk2(c2.x,c2.y); g[5]=mk2(c2.z,c2.w); \
    g[6]=mk2(c3.x,c3.y); g[7]=mk2(c3.z,c3.w); \
    { f2 A2=splat2(A), B2=splat2(Bst); \
      _Pragma("unroll") for (int p=0;p<8;p++){ \
        g[p]=fma2(m0v[p],A2,g[p]); g[p]=fma2(m1v[p],B2,g[p]); } } \
    f2 rr[8]; \
    _Pragma("unroll") for (int p=0;p<8;p++){ \
      f2 ex = mk2(EXPG(g[p].x), EXPG(g[p].y)); \
      f2 dd = mk2(ex.x+1.f, ex.y+1.f); \
      rr[p] = mk2(__builtin_amdgcn_rcpf(dd.x), __builtin_amdgcn_rcpf(dd.y)); } \
    f2 ua=mk2(0.f,0.f), ub=mk2(0.f,0.f), uc=mk2(0.f,0.f), ud=mk2(0.f,0.f); \
    _Pragma("unroll") for (int p=0;p<4;p++){ ua=fma2(rr[p],n0v[p],ua); ub=fma2(rr[p],n1v[p],ub); } \
    _Pragma("unroll") for (int p=4;p<8;p++){ uc=fma2(rr[p],n0v[p],uc); ud=fma2(rr[p],n1v[p],ud); } \
    float u0=(ua.x+ua.y)+(uc.x+uc.y); \
    float u1=(ub.x+ub.y)+(ud.x+ud.y); \
    wave64_sum2(u0,u1); \
    float U0 = N0 + RD63(u0); \
    float U1 = N1 + RD63(u1); \
    A   = fmaf(CA, U0, OMA*A); \
    Bst = fmaf(CA, U1, OMA*Bst); \
    if (lane<2){ \
      float add = lane==0 ? SCL*U0 : SCL*U1; \
      o = fmaf(OMA, o, ALPHA*add); \
      outb[(T)*10+lane]=o; } \
  }

    #pragma unroll 1
    for (int c=0;c<SEQ/CH;c++){
      while (*vpr < c+1) ;               // steady state: already satisfied
      asm volatile("" ::: "memory");     // no P reads hoisted above the poll
      const int buf = c&1;
      f4 cA0=Pb[buf][0][0][lane], cA1=Pb[buf][0][1][lane],
         cA2=Pb[buf][0][2][lane], cA3=Pb[buf][0][3][lane];
      f4 cB0,cB1,cB2,cB3;
      const int t0 = c*CH;
      #pragma unroll 1
      for (int tt=0; tt<CH; tt+=2){
        STEP(t0+tt,   tt+1,          buf, cA0,cA1,cA2,cA3, cB0,cB1,cB2,cB3)
        STEP(t0+tt+1, (tt+2)&(CH-1), buf, cB0,cB1,cB2,cB3, cA0,cA1,cA2,cA3)
      }
      asm volatile("" ::: "memory");     // P reads issued before flag
      if (lane==0) *vcd = c+1;
    }
  #undef STEP
  }

  __syncthreads();   // outb complete (both waves)
  const f4* ob4 = (const f4*)outb;
  f4* o4 = (f4*)out + (size_t)b*(SEQ*10/4);
  for (int idx=tid; idx<SEQ*10/4; idx+=128) o4[idx]=ob4[idx];
}

extern "C" void kernel_launch(void* const* d_in, const int* in_sizes, int n_in,
                              void* d_out, int out_size, void* d_ws, size_t ws_size,
                              hipStream_t stream) {
  const float* x     = (const float*)d_in[0];  // (64,512,8)
  const float* eps   = (const float*)d_in[1];  // (4,1024,12)
  const float* means = (const float*)d_in[2];  // (4,12)
  const float* tril  = (const float*)d_in[3];  // (4,12,12)
  const float* mw    = (const float*)d_in[4];  // (4,)
  float* out = (float*)d_out;                  // (64,512,10) fp32

  rnn_scan<<<NBAT, 128, 0, stream>>>(x, eps, means, tril, mw, out);
}

// Round 9
// 269.428 us; speedup vs baseline: 1.1195x; 1.1195x over previous
//
#include <hip/hip_runtime.h>

#define HS   1024
#define SEQ  512
#define NBAT 64
#define INSZ 8
#define NM   4
#define DD   12
#define WV   8      // 8 waves = 2 per SIMD -> TLP fills chain stalls

#define ALPHA 0.1f
#define OMA   0.9f
#define SCL   (500.0f/1024.0f)
#define AS    (ALPHA*SCL)

// exp(2h) as exp2(hs) where hs = 2*log2(e)*h (state pre-scaled).
#if __has_builtin(__builtin_amdgcn_exp2f)
  #define GSC 2.8853900817779268f     /* 2*log2(e) */
  #define EXPG(v) __builtin_amdgcn_exp2f(v)
#else
  #define GSC 2.0f
  #define EXPG(v) __expf(v)
#endif

typedef float f2 __attribute__((ext_vector_type(2)));
typedef float f4 __attribute__((ext_vector_type(4)));
__device__ __forceinline__ f2 mk2(float a, float b){ f2 r; r.x=a; r.y=b; return r; }
__device__ __forceinline__ f2 splat2(float a){ return mk2(a,a); }
#if __has_builtin(__builtin_elementwise_fma)
__device__ __forceinline__ f2 fma2(f2 a, f2 b, f2 c){ return __builtin_elementwise_fma(a,b,c); }
#else
__device__ __forceinline__ f2 fma2(f2 a, f2 b, f2 c){
  f2 r; r.x=fmaf(a.x,b.x,c.x); r.y=fmaf(a.y,b.y,c.y); return r; }
#endif

// DPP-based add: v += dpp_move(v). old=0 so masked/invalid lanes add 0.
#define DPP_ADD(v, ctrl, rmask, bmask) \
  v += __int_as_float(__builtin_amdgcn_update_dpp(0, __float_as_int(v), ctrl, rmask, bmask, true))

// Canonical gfx9 wave64 sum. Lane 63 holds the full 64-lane total afterwards.
__device__ __forceinline__ void wave64_sum2(float &a, float &b){
  DPP_ADD(a, 0x111, 0xf, 0xf); DPP_ADD(b, 0x111, 0xf, 0xf);  // row_shr:1
  DPP_ADD(a, 0x112, 0xf, 0xf); DPP_ADD(b, 0x112, 0xf, 0xf);  // row_shr:2
  DPP_ADD(a, 0x114, 0xf, 0xe); DPP_ADD(b, 0x114, 0xf, 0xe);  // row_shr:4
  DPP_ADD(a, 0x118, 0xf, 0xc); DPP_ADD(b, 0x118, 0xf, 0xc);  // row_shr:8
  DPP_ADD(a, 0x142, 0xa, 0xf); DPP_ADD(b, 0x142, 0xa, 0xf);  // row_bcast:15
  DPP_ADD(a, 0x143, 0xc, 0xf); DPP_ADD(b, 0x143, 0xc, 0xf);  // row_bcast:31
}

// mixed[e] for unit i, e in [0,12)
__device__ __forceinline__ void mix_unit(int i, const float* __restrict__ eps,
                                         const float* __restrict__ means,
                                         const float* __restrict__ tril,
                                         const float* w, float* outm){
  float ep[NM][DD];
  #pragma unroll
  for (int k=0;k<NM;k++){
    const float4* p = (const float4*)(eps + (size_t)(k*HS + i)*DD);
    float4 r0=p[0], r1=p[1], r2=p[2];
    ep[k][0]=r0.x; ep[k][1]=r0.y; ep[k][2]=r0.z; ep[k][3]=r0.w;
    ep[k][4]=r1.x; ep[k][5]=r1.y; ep[k][6]=r1.z; ep[k][7]=r1.w;
    ep[k][8]=r2.x; ep[k][9]=r2.y; ep[k][10]=r2.z; ep[k][11]=r2.w;
  }
  #pragma unroll
  for (int e=0;e<DD;e++){
    float a = 0.f;
    #pragma unroll
    for (int k=0;k<NM;k++){
      float se = means[k*DD+e];
      #pragma unroll
      for (int d=0; d<e; d++) se = fmaf(ep[k][d], tril[(k*DD+e)*DD+d], se);
      float dg = fabsf(tril[(k*DD+e)*DD+e] - 1e-12f) + 1e-12f;
      se = fmaf(ep[k][e], dg, se);
      a = fmaf(w[k], se, a);
    }
    outm[e] = a;
  }
}

// 8 waves x 2 units/lane: 2 waves per SIMD so one wave's issue fills the other
// wave's chain stalls (trans latency, 6-stage DPP, post-barrier LDS read).
// Same verified per-unit math as the 4-wave version; pre-barrier hpre moves
// half the h-update off the serial chain.
__global__ __launch_bounds__(512,1)
void rnn_scan(const float* __restrict__ x, const float* __restrict__ eps,
              const float* __restrict__ means, const float* __restrict__ tril,
              const float* __restrict__ mw, float* __restrict__ out)
{
  const int b    = blockIdx.x;
  const int tid  = threadIdx.x;
  const int wave = tid >> 6;
  const int lane = tid & 63;

  __shared__ float xs[SEQ*INSZ];                 // 16 KB
  __shared__ __align__(16) f2 red[2][WV];        // double-buffered wave partials
  __shared__ __align__(16) float outb[SEQ*10];   // 20 KB

  // stage x[b] (coalesced f4, 512 threads)
  { const f4* xp=(const f4*)(x + (size_t)b*SEQ*INSZ);
    f4* xd=(f4*)xs;
    for (int idx=tid; idx<SEQ*INSZ/4; idx+=512) xd[idx]=xp[idx]; }

  float w[NM];
  { float s=0.f;
    #pragma unroll
    for (int k=0;k<NM;k++){ w[k]=fmaxf(mw[k],1e-6f); s+=w[k]; }
    float inv=1.0f/s;
    #pragma unroll
    for (int k=0;k<NM;k++) w[k]*=inv; }

  // ---- per-thread params: units tid (comp .x) and tid+512 (comp .y) ----
  // m0g/m1g carry GSC*AS; n0v/n1v carry -2n; ALG=GSC*ALPHA folds into inj.
  f2 m0g, m1g, n0v, n1v, I2[8];
  float pn0, pn1;
  {
    float mmA[DD], mmB[DD];
    mix_unit(tid,       eps, means, tril, w, mmA);
    mix_unit(tid + 512, eps, means, tril, w, mmB);
    m0g = mk2((GSC*AS)*mmA[0], (GSC*AS)*mmB[0]);
    m1g = mk2((GSC*AS)*mmA[1], (GSC*AS)*mmB[1]);
    n0v = mk2(-2.f*mmA[2],     -2.f*mmB[2]);
    n1v = mk2(-2.f*mmA[3],     -2.f*mmB[3]);
    pn0 = mmA[2]+mmB[2];
    pn1 = mmA[3]+mmB[3];
    #pragma unroll
    for (int e=0;e<8;e++) I2[e] = mk2(mmA[4+e], mmB[4+e]);
  }

  // ---- N0,N1 = sum of n over ALL 1024 units (one-time reduce) ----
  wave64_sum2(pn0, pn1);
  if (lane==63) red[0][wave] = mk2(pn0,pn1);
  __syncthreads();
  float N0, N1;
  { const f4* rq = (const f4*)&red[0][0];
    f4 Q0=rq[0], Q1=rq[1], Q2=rq[2], Q3=rq[3];
    f4 S = (Q0+Q1)+(Q2+Q3);          // S = [u0 evens, u1 evens, u0 odds, u1 odds]
    N0 = S.x + S.z;  N1 = S.y + S.w; }
  __syncthreads();   // red[0] consumed before step 0 overwrites it

  const float ALG = GSC*ALPHA;
  f2 hs = mk2(0.f,0.f);
  float o = 0.f;

  const f4* xs4 = (const f4*)xs;
  f4 xa = xs4[0], xb = xs4[1];       // x_0 prefetched

  #pragma unroll 2
  for (int t=0;t<SEQ;t++){
    // r = rcp(exp2(hs)+1); partial u = -2n . r (the only coupled part)
    float e0=EXPG(hs.x), e1=EXPG(hs.y);
    f2 rq = mk2(__builtin_amdgcn_rcpf(e0+1.f), __builtin_amdgcn_rcpf(e1+1.f));
    f2 s0 = rq*n0v, s1 = rq*n1v;
    float u0 = s0.x+s0.y, u1 = s1.x+s1.y;
    wave64_sum2(u0,u1);                           // DPP butterfly -> lane 63
    if (lane==63) red[t&1][wave] = mk2(u0,u1);

    // off-chain while partials land: inj = x_t . I, hpre = 0.9*hs + ALG*inj
    f2 inj;
    { f2 a =      I2[0]*splat2(xa.x);
      a = fma2(I2[1], splat2(xa.y), a);
      a = fma2(I2[2], splat2(xa.z), a);
      a = fma2(I2[3], splat2(xa.w), a);
      a = fma2(I2[4], splat2(xb.x), a);
      a = fma2(I2[5], splat2(xb.y), a);
      a = fma2(I2[6], splat2(xb.z), a);
      a = fma2(I2[7], splat2(xb.w), a);
      inj = a; }
    f2 hpre = fma2(splat2(OMA), hs, inj*splat2(ALG));
    // prefetch x_{t+1} (wraps harmlessly at the final step)
    { const int tn = (t+1)&(SEQ-1); xa = xs4[tn*2]; xb = xs4[tn*2+1]; }

    __syncthreads();
    float U0, U1;
    { const f4* rr = (const f4*)&red[t&1][0];
      f4 Q0=rr[0], Q1=rr[1], Q2=rr[2], Q3=rr[3];
      f4 S = (Q0+Q1)+(Q2+Q3);
      U0 = N0 + (S.x + S.z);
      U1 = N1 + (S.y + S.w); }

    // on-chain: only 2 dependent fmas to the new state
    hs = fma2(m0g, splat2(U0), fma2(m1g, splat2(U1), hpre));

    // o_t = pinv(span) @ h_t exactly (h lives in col(span), pinv@span = I_10)
    if (tid < 10){
      float add = (tid==0) ? SCL*U0 : (tid==1) ? SCL*U1 : xs[t*8 + tid-2];
      o = __builtin_fmaf(OMA, o, ALPHA*add);
      outb[t*10+tid] = o;
    }
  }

  __syncthreads();
  // burst-dump staged outputs, coalesced float4
  const f4* ob4 = (const f4*)outb;
  f4* o4 = (f4*)out + (size_t)b*(SEQ*10/4);
  for (int idx=tid; idx<SEQ*10/4; idx+=512) o4[idx]=ob4[idx];
}

extern "C" void kernel_launch(void* const* d_in, const int* in_sizes, int n_in,
                              void* d_out, int out_size, void* d_ws, size_t ws_size,
                              hipStream_t stream) {
  const float* x     = (const float*)d_in[0];  // (64,512,8)
  const float* eps   = (const float*)d_in[1];  // (4,1024,12)
  const float* means = (const float*)d_in[2];  // (4,12)
  const float* tril  = (const float*)d_in[3];  // (4,12,12)
  const float* mw    = (const float*)d_in[4];  // (4,)
  float* out = (float*)d_out;                  // (64,512,10) fp32

  rnn_scan<<<NBAT, 512, 0, stream>>>(x, eps, means, tril, mw, out);
}